// Round 11
// baseline (363.534 us; speedup 1.0000x reference)
//
#include <hip/hip_runtime.h>

// GCN-TCN unit. All GEMM-shaped work on bf16 MFMA; swizzled global layouts
// (chunk q of each 64B row stored at position q ^ key(row), key(r) = (r^(r>>2))&3)
// kill LDS bank conflicts while keeping global_load_lds staging purely linear.
// Shapes: N=32, C=128, T=256, V=25, K=5.
//
//   k0 : init stats, Wd -> WdB bf16 linear, Wt -> Wt_b bf16 swz(o)
//   k1a: g = x@PA -> gT bf16 [n][cc][col][c32]~swz(col)  (PA transposed in LDS;
//        vectorized output: ds_read_b128 + dwordx4, rows padded to 20 dw)
//   k1b: y0 = Wd@g + bd -> y0b bf16 + statsY   (MFMA K=128, B dbuf, A from global/L2)
//   k2 : yhat = relu(inorm(y0)+x) -> yhatT ~swz(col)  (aliases gT; vectorized
//        output stores: 4x scalar LDS gather -> 1x dwordx4)
//   k3 : z = conv(yhat) + bt -> zb bf16 (aliases y0b) + statsZ
//        (r5-converged: 64o x 256c, grid 1600, 3 blocks/CU, A LDS-staged,
//         B reg-prefetch w/ counted vmcnt, XCD swizzle, setprio)
//   k4 : out = relu(inorm(z)+x) -> d_out fp32 (nontemporal out stores via
//        ext-vector floatx4 -- __builtin_nontemporal_store rejects HIP float4)
//
// Ledger: r6 xb refuted (x is L3-resident); r7 A-direct+1-barrier spilled;
// r8 128c tile refuted (per-phase overhead bound). k3 converged at r5 config.

typedef unsigned short u16;
typedef unsigned int   u32;

using short8  = __attribute__((ext_vector_type(8))) short;
using floatx4 = __attribute__((ext_vector_type(4))) float;
using u32x4   = __attribute__((ext_vector_type(4))) unsigned int;

#define NBATCH 32
#define CH     128
#define TDIM   256
#define VDIM   25
#define KT     5
#define PLANE  6400
#define EPSF   1e-5f
#define INV_PLANE (1.0f/6400.0f)

__device__ __forceinline__ u16 f2bf(float f) {          // RNE fp32 -> bf16
    u32 u = __float_as_uint(f);
    return (u16)((u + 0x7fffu + ((u >> 16) & 1u)) >> 16);
}
__device__ __forceinline__ float bf2f(u16 h) {
    return __uint_as_float(((u32)h) << 16);
}
__device__ __forceinline__ void gload_lds16(const void* g, void* l) {
    __builtin_amdgcn_global_load_lds(
        (const __attribute__((address_space(1))) u32*)g,
        (__attribute__((address_space(3))) u32*)l, 16, 0, 0);
}

// ---------------- K0: init stats + weight repack ----------------
// WdB linear (k1b reads fragments straight from global/L2).
// Wt_b swizzled with key(o) = (o^(o>>2))&3 (k3 stages linearly; reads use key).
__global__ __launch_bounds__(256) void k0_init(
    const float* __restrict__ Wd, const float* __restrict__ Wt,
    float* __restrict__ statsY, float* __restrict__ statsZ,
    u16* __restrict__ WdB, u16* __restrict__ Wt_b)
{
    int i = blockIdx.x * 256 + threadIdx.x;       // grid covers exactly 114688
    if (i < 8192) {
        statsY[i] = 0.f;
    } else if (i < 16384) {
        statsZ[i - 8192] = 0.f;
    } else if (i < 32768) {
        int j  = i - 16384;                       // WdB[cc][o][c32] linear
        int sl = j & 31;
        int o  = (j >> 5) & 127;
        int cc = j >> 12;
        WdB[j] = f2bf(Wd[o * CH + cc * 32 + sl]);
    } else {
        int j  = i - 32768;                       // Wt_b[ic][tap][o][stored i-slot]~swz(o)
        int sl = j & 31;
        int o  = (j >> 5) & 127;
        int r2 = j >> 12;
        int tap = r2 % KT;
        int ic  = r2 / KT;
        int ko = ((o ^ (o >> 2)) & 3);
        int il = (((sl >> 3) ^ ko) << 3) | (sl & 7);
        Wt_b[j] = f2bf(Wt[(o * CH + ic * 32 + il) * KT + tap]);
    }
}

// ---------------- K1a: g = x@PA -> gT bf16 [n][cc][col][c32]~swz ----------------
// grid (16, 128): blockIdx.x = 400-col chunk (16 t-rows), blockIdx.y = n*4+cc.
// PA stored transposed+padded (sPA[v*28+w]) so the inner loop reads stride-1.
// sG rows padded to 20 dwords; output stage moves whole 16B q-chunks.
__global__ __launch_bounds__(256) void k1a_gcn(
    const float* __restrict__ x, const float* __restrict__ PA,
    u16* __restrict__ gT)
{
    __shared__ __attribute__((aligned(16))) u32 sG[400 * 20];  // 400 rows x 20 dw (pad)
    __shared__ __attribute__((aligned(16))) float sPA[700];    // [v][28] transposed

    const int tid   = threadIdx.x;
    const int nic   = blockIdx.y;
    const int chunk = blockIdx.x;
    const int c0    = chunk * 400;                // 400 = 0 mod 16 -> local key form OK
    const int cl    = tid >> 3;
    const int tl    = tid & 7;

    for (int i = tid; i < 700; i += 256) {
        int v = i / 28, w = i % 28;
        sPA[i] = (w < VDIM) ? PA[w * VDIM + v] : 0.f;
    }

    const float* xrow = x + (size_t)(nic * 32 + cl) * PLANE + c0 + tl * 50;
    float xr[50];
#pragma unroll
    for (int w = 0; w < 25; ++w) {
        float2 t2 = *(const float2*)(xrow + 2 * w);
        xr[2 * w]     = t2.x;
        xr[2 * w + 1] = t2.y;
    }
    __syncthreads();

    u16* sG16 = (u16*)sG;
#pragma unroll
    for (int v = 0; v < VDIM; ++v) {
        float g0 = 0.f, g1 = 0.f;
        const float* pav = &sPA[v * 28];
#pragma unroll
        for (int w = 0; w < VDIM; ++w) {
            float p = pav[w];                     // stride-1, wave-uniform broadcast
            g0 += xr[w] * p;
            g1 += xr[25 + w] * p;
        }
        int r0 = tl * 50 + v;
        sG16[r0 * 40 + cl]        = f2bf(g0);
        sG16[(r0 + 25) * 40 + cl] = f2bf(g1);
    }
    __syncthreads();

    u32* outd = (u32*)gT;
    const size_t ob = ((size_t)nic * PLANE + c0) * 16;
    for (int g4 = tid; g4 < 1600; g4 += 256) {    // 1600 16B q-chunks
        int r = g4 >> 2, q = g4 & 3;
        int kr = ((r ^ (r >> 2)) & 3);
        u32x4 v = *(const u32x4*)(sG + r * 20 + q * 4);
        *(u32x4*)(outd + ob + r * 16 + ((q ^ kr) << 2)) = v;
    }
}

// ---------------- K1b: y0 = Wd@g + bd via bf16 MFMA, K=128 ----------------
__global__ __launch_bounds__(256) void k1b_mfma(
    const u16* __restrict__ gT, const u16* __restrict__ WdB,
    const float* __restrict__ bd,
    u16* __restrict__ y0b, float* __restrict__ statsY)
{
    __shared__ __attribute__((aligned(16))) char lds[16384];   // 2 x 8KB B buffers

    const int tid  = threadIdx.x;
    const int wave = tid >> 6;
    const int lane = tid & 63;
    const int l    = lane & 15;
    const int quad = lane >> 4;
    const int n    = blockIdx.y;
    const int c0   = blockIdx.x * 128;            // mult of 16 -> local key form OK
    const int wub  = tid & ~63;

    auto stageB = [&](int cc, char* dst) {
        const char* bsrc = (const char*)gT + ((size_t)(n * 4 + cc) * PLANE + c0) * 64;
#pragma unroll
        for (int it = 0; it < 2; ++it)
            gload_lds16(bsrc + (it * 256 + tid) * 16, dst + (it * 256 + wub) * 16);
    };

    stageB(0, lds);
    __syncthreads();

    floatx4 acc[2][8];
#pragma unroll
    for (int a = 0; a < 2; ++a)
#pragma unroll
        for (int b = 0; b < 8; ++b) acc[a][b] = (floatx4){0.f, 0.f, 0.f, 0.f};

    for (int cc = 0; cc < 4; ++cc) {
        char* const sBc = lds + (cc & 1) * 8192;
        char* const sBn = lds + ((cc + 1) & 1) * 8192;

        // A fragments from global: lanes cover 16 consecutive 64B rows (coalesced)
        const char* abase = (const char*)WdB + cc * 8192 + (wave * 32 + l) * 64 + (quad << 4);
        const short8 a0 = *(const short8*)(abase);
        const short8 a1 = *(const short8*)(abase + 16 * 64);
        __builtin_amdgcn_sched_barrier(0);        // af loads issue before staging

        if (cc < 3) stageB(cc + 1, sBn);

#pragma unroll
        for (int ct = 0; ct < 8; ++ct) {
            const int r = ct * 16 + l;
            const short8 b = *(const short8*)(sBc + r * 64 + ((quad ^ ((r ^ (r >> 2)) & 3)) << 4));
            acc[0][ct] = __builtin_amdgcn_mfma_f32_16x16x32_bf16(a0, b, acc[0][ct], 0, 0, 0);
            acc[1][ct] = __builtin_amdgcn_mfma_f32_16x16x32_bf16(a1, b, acc[1][ct], 0, 0, 0);
        }
        __syncthreads();
    }

#pragma unroll
    for (int ot = 0; ot < 2; ++ot) {
#pragma unroll
        for (int reg = 0; reg < 4; ++reg) {
            const int o = wave * 32 + ot * 16 + quad * 4 + reg;
            const float bias = bd[o];
            float s1 = 0.f, s2 = 0.f;
            u16* yp = y0b + (size_t)(n * CH + o) * PLANE + c0 + l;
#pragma unroll
            for (int ct = 0; ct < 8; ++ct) {
                float val = acc[ot][ct][reg] + bias;
                yp[ct * 16] = f2bf(val);
                s1 += val; s2 += val * val;
            }
#pragma unroll
            for (int m = 1; m <= 8; m <<= 1) {
                s1 += __shfl_xor(s1, m, 64);
                s2 += __shfl_xor(s2, m, 64);
            }
            if (l == 0) {
                atomicAdd(&statsY[(n * CH + o) * 2 + 0], s1);
                atomicAdd(&statsY[(n * CH + o) * 2 + 1], s2);
            }
        }
    }
}

// ---------------- K2: yhat = relu(inorm(y0)+x) -> yhatT bf16 ~swz ----------------
// Output stage: per (row, q-chunk) gather 4 permuted dwords from sT (scalar LDS
// reads, 17-stride keeps banks spread) -> one global dwordx4; wave writes 1KB
// contiguous. 16 scalar stores -> 4 vector stores per thread.
__global__ __launch_bounds__(256) void k2_yhat(
    const u16* __restrict__ y0b, const float* __restrict__ x,
    const float* __restrict__ statsY, u16* __restrict__ yhatT)
{
    __shared__ u32 sT[256 * 17];
    __shared__ float sM[32], sR[32];

    const int tid = threadIdx.x;
    const int nic = blockIdx.y;
    const int n   = nic >> 2, ic = nic & 3;
    const int c0  = blockIdx.x * 256;             // mult of 16 -> local key form OK

    if (tid < 32) {
        float a = statsY[(n * CH + ic * 32 + tid) * 2 + 0];
        float b = statsY[(n * CH + ic * 32 + tid) * 2 + 1];
        float m = a * INV_PLANE;
        sM[tid] = m;
        sR[tid] = rsqrtf(b * INV_PLANE - m * m + EPSF);
    }
    __syncthreads();

    u16* sT16 = (u16*)sT;
#pragma unroll
    for (int k = 0; k < 4; ++k) {
        int j  = k * 256 + tid;                   // 0..1023
        int ch = j >> 5;                          // 0..31
        int cb = (j & 31) << 3;                   // col base, 8-aligned
        int g  = (n * CH + ic * 32 + ch) * PLANE + c0 + cb;
        short8 yv = *(const short8*)(y0b + g);
        const float4* xp = (const float4*)(x + g);
        float4 x0 = xp[0], x1 = xp[1];
        float xf[8];
        xf[0] = x0.x; xf[1] = x0.y; xf[2] = x0.z; xf[3] = x0.w;
        xf[4] = x1.x; xf[5] = x1.y; xf[6] = x1.z; xf[7] = x1.w;
        float m = sM[ch], r = sR[ch];
        int wp = ((ch >> 1) ^ ((cb >> 3) & 15));  // swizzled pair index
        u16* dst = sT16 + cb * 34 + wp * 2 + (ch & 1);
#pragma unroll
        for (int e = 0; e < 8; ++e)
            dst[e * 34] = f2bf(fmaxf((bf2f((u16)yv[e]) - m) * r + xf[e], 0.f));
    }
    __syncthreads();

    u32* outd = (u32*)yhatT;
    int obase = (nic * PLANE + c0) * 16;
    for (int idx4 = tid; idx4 < 1024; idx4 += 256) {   // 1024 (row, q-chunk) pairs
        int r = idx4 >> 2, q = idx4 & 3;
        int p = (r >> 3) & 15;                         // pair-unswizzle key
        u32x4 v;
#pragma unroll
        for (int b = 0; b < 4; ++b)
            v[b] = sT[r * 17 + (((q * 4 + b) ^ p) & 15)];
        int kr = ((r ^ (r >> 2)) & 3);
        *(u32x4*)(outd + obase + r * 16 + ((q ^ kr) << 2)) = v;
    }
}

// ---------------- K3: TCN conv via bf16 MFMA, 64o x 256c blocks (r5) ----------------
// grid 1600 (1D, XCD-swizzled): id&7 = XCD, each XCD owns n in [4*xcd, 4*xcd+4).
// 4 waves, each 32o x 128c -> acc[2][8] = 64 AGPRs; LDS 45KB -> 3 blocks/CU.
// B register-prefetch pipeline w/ counted vmcnt (5 A-DMAs + 6 B-loads in flight
// -> vmcnt(6) drains exactly A, keeps B in flight). LDS reads use (r>>2)-folded
// key; local B rows at global offset c0-100 -> local key (r&3)^(((r>>2)+3)&3).
__global__ __launch_bounds__(256, 3) void k3_mfma(
    const u16* __restrict__ yhatT, const u16* __restrict__ Wt_b,
    const float* __restrict__ bt,
    u16* __restrict__ zb, float* __restrict__ statsZ)
{
    __shared__ __attribute__((aligned(16))) char lds[45056];
    char* const sA = lds;            // [tap][64 o][32 i] bf16 = 20480 B
    char* const sB = lds + 20480;    // [row 0..384)[32 i] bf16 = 24576 B

    const int tid  = threadIdx.x;
    const int wave = tid >> 6;
    const int wr2  = wave >> 1;      // 32-o half within the block's 64 o
    const int wc   = wave & 1;       // col 128-half
    const int lane = tid & 63;
    const int l    = lane & 15;
    const int quad = lane >> 4;
    const int id   = blockIdx.x;     // XCD-aware decomposition (1600 blocks)
    const int xcd  = id & 7;
    const int jj   = id >> 3;        // 0..199
    const int n    = xcd * 4 + jj / 50;
    const int rem  = jj % 50;
    const int oh   = rem / 25;       // which 64-o half
    const int blk  = rem % 25;
    const int c0   = blk * 256;
    const int wub  = tid & ~63;
    const bool mainp = (blk != 0);

    floatx4 acc[2][8];
#pragma unroll
    for (int a = 0; a < 2; ++a)
#pragma unroll
        for (int b = 0; b < 8; ++b) acc[a][b] = (floatx4){0.f, 0.f, 0.f, 0.f};

    auto bsrcIC = [&](int ic) -> const char* {
        return (const char*)yhatT + ((size_t)(n * 4 + ic) * PLANE) * 64
             + (size_t)(c0 - 100) * 64;
    };

    short8 breg[6];
    if (mainp) {
#pragma unroll
        for (int it = 0; it < 6; ++it)
            breg[it] = *(const short8*)(bsrcIC(0) + (it * 256 + tid) * 16);
    }

    for (int ic = 0; ic < 4; ++ic) {
        __syncthreads();             // prev MFMA consumed LDS; drains all counters

        // stage A: 5 taps x 4096 B async DMA (L2-resident weights, this o-half)
#pragma unroll
        for (int tap = 0; tap < KT; ++tap)
            gload_lds16((const char*)Wt_b + ic * 40960 + (tap * 128 + oh * 64) * 64 + tid * 16,
                        sA + tap * 4096 + wub * 16);
        __builtin_amdgcn_sched_barrier(0);        // A issues first (oldest in queue)

        if (mainp) {
            // write current B tile from regs (compiler waits breg deps)
#pragma unroll
            for (int it = 0; it < 6; ++it)
                *((short8*)(sB + (it * 256 + tid) * 16)) = breg[it];
            if (ic < 3) {
                const char* nb = bsrcIC(ic + 1);
                __builtin_amdgcn_sched_barrier(0);
#pragma unroll
                for (int it = 0; it < 6; ++it)    // exactly 6 vm ops, newest
                    breg[it] = *(const short8*)(nb + (it * 256 + tid) * 16);
                __builtin_amdgcn_sched_barrier(0);
                asm volatile("s_waitcnt vmcnt(6) lgkmcnt(0)" ::: "memory");
            } else {
                asm volatile("s_waitcnt vmcnt(0) lgkmcnt(0)" ::: "memory");
            }
        } else {
            // blk==0: rows 100..356 <- cols 0..256 via DMA; rows 0..100 reflected
            const char* bsrc = (const char*)yhatT + ((size_t)(n * 4 + ic) * PLANE) * 64;
#pragma unroll
            for (int it = 0; it < 4; ++it)
                gload_lds16(bsrc + (it * 256 + tid) * 16, sB + 6400 + (it * 256 + wub) * 16);
            const u32* bsrcd = (const u32*)bsrc;
            u32* sBd = (u32*)sB;
            for (int idx = tid; idx < 1600; idx += 256) {
                int r = idx >> 4, dw = idx & 15;
                int q = dw >> 2, b = dw & 3;
                int d = 100 - r;
                int tref = (d + 24) / 25;
                int v = r % 25;
                int sc = tref * 25 + v;
                int kd = ((r ^ ((r >> 2) + 3)) & 3);        // local-key for dst row
                int ks = ((sc ^ (sc >> 2)) & 3);            // global-key for src row
                sBd[r * 16 + (((q ^ kd) << 2) | b)] =
                    bsrcd[sc * 16 + (((q ^ ks) << 2) | b)];
            }
            asm volatile("s_waitcnt vmcnt(0) lgkmcnt(0)" ::: "memory");
        }
        __builtin_amdgcn_s_barrier();
        __builtin_amdgcn_sched_barrier(0);        // pin ds_reads below the barrier

        __builtin_amdgcn_s_setprio(1);
#pragma unroll
        for (int tap = 0; tap < KT; ++tap) {
            short8 af[2];
#pragma unroll
            for (int ot = 0; ot < 2; ++ot) {
                int ro = wr2 * 32 + ot * 16 + l;
                af[ot] = *(const short8*)(sA + tap * 4096 + ro * 64
                                          + ((quad ^ ((ro ^ (ro >> 2)) & 3)) << 4));
            }
#pragma unroll
            for (int ct = 0; ct < 8; ++ct) {
                int r = wc * 128 + ct * 16 + l + tap * 25;
                const short8 b = *(const short8*)(sB + r * 64
                                          + ((quad ^ ((r ^ ((r >> 2) + 3)) & 3)) << 4));
#pragma unroll
                for (int ot = 0; ot < 2; ++ot)
                    acc[ot][ct] = __builtin_amdgcn_mfma_f32_16x16x32_bf16(af[ot], b, acc[ot][ct], 0, 0, 0);
            }
        }
        __builtin_amdgcn_s_setprio(0);
    }

    // epilogue: bias + bf16 store + stats (C/D: col=lane&15, row=quad*4+reg)
#pragma unroll
    for (int ot = 0; ot < 2; ++ot) {
#pragma unroll
        for (int reg = 0; reg < 4; ++reg) {
            const int o = oh * 64 + wr2 * 32 + ot * 16 + quad * 4 + reg;
            const float bias = bt[o];
            float s1 = 0.f, s2 = 0.f;
            u16* zp = zb + (size_t)(n * CH + o) * PLANE + c0 + wc * 128 + l;
#pragma unroll
            for (int ct = 0; ct < 8; ++ct) {
                float val = acc[ot][ct][reg] + bias;
                zp[ct * 16] = f2bf(val);
                s1 += val; s2 += val * val;
            }
#pragma unroll
            for (int m = 1; m <= 8; m <<= 1) {
                s1 += __shfl_xor(s1, m, 64);
                s2 += __shfl_xor(s2, m, 64);
            }
            if (l == 0) {
                atomicAdd(&statsZ[(n * CH + o) * 2 + 0], s1);
                atomicAdd(&statsZ[(n * CH + o) * 2 + 1], s2);
            }
        }
    }
}

// ---------------- K4: out = relu(inorm(zb) + x) -> d_out ----------------
// out is write-once, never re-read: nontemporal stores keep the 210MB stream
// from evicting x/zb lines in L2/L3. Uses ext-vector floatx4 (the builtin
// rejects HIP_vector_type float4).
__global__ __launch_bounds__(256) void k4_final(
    const u16* __restrict__ zb, const float* __restrict__ x,
    const float* __restrict__ statsZ, float* __restrict__ out)
{
    int g = blockIdx.x * 256 + threadIdx.x;       // 3,276,800 threads x 8 elems
    int p = g / 800;
    float a = statsZ[p * 2 + 0], b = statsZ[p * 2 + 1];
    float m = a * INV_PLANE;
    float r = rsqrtf(b * INV_PLANE - m * m + EPSF);
    short8 zv = *(const short8*)(zb + (size_t)g * 8);
    const float4* xp = (const float4*)x + (size_t)g * 2;
    float4 x0 = xp[0], x1 = xp[1];
    floatx4 o0, o1;
    o0[0] = fmaxf((bf2f((u16)zv[0]) - m) * r + x0.x, 0.f);
    o0[1] = fmaxf((bf2f((u16)zv[1]) - m) * r + x0.y, 0.f);
    o0[2] = fmaxf((bf2f((u16)zv[2]) - m) * r + x0.z, 0.f);
    o0[3] = fmaxf((bf2f((u16)zv[3]) - m) * r + x0.w, 0.f);
    o1[0] = fmaxf((bf2f((u16)zv[4]) - m) * r + x1.x, 0.f);
    o1[1] = fmaxf((bf2f((u16)zv[5]) - m) * r + x1.y, 0.f);
    o1[2] = fmaxf((bf2f((u16)zv[6]) - m) * r + x1.z, 0.f);
    o1[3] = fmaxf((bf2f((u16)zv[7]) - m) * r + x1.w, 0.f);
    floatx4* op = (floatx4*)out + (size_t)g * 2;
    __builtin_nontemporal_store(o0, op);
    __builtin_nontemporal_store(o1, op + 1);
}

extern "C" void kernel_launch(void* const* d_in, const int* in_sizes, int n_in,
                              void* d_out, int out_size, void* d_ws, size_t ws_size,
                              hipStream_t stream) {
    const float* x  = (const float*)d_in[0];
    const float* PA = (const float*)d_in[1];
    const float* Wd = (const float*)d_in[2];
    const float* bd = (const float*)d_in[3];
    const float* Wt = (const float*)d_in[4];
    const float* bt = (const float*)d_in[5];
    float* out = (float*)d_out;

    char* wsb = (char*)d_ws;
    u16*   y0b    = (u16*)(wsb);                   // 52,428,800 B (aliased by zb)
    u16*   zb     = y0b;                           //   y0b consumed by k2 before k3 writes
    u16*   gT     = (u16*)(wsb + 52428800);        // 52,428,800 B (aliased by yhatT)
    u16*   yhatT  = gT;                            //   gT consumed by k1b before k2 writes
    float* statsY = (float*)(wsb + 104857600);     // 32,768 B
    float* statsZ = (float*)(wsb + 104890368);     // 32,768 B
    u16*   WdB    = (u16*)(wsb + 104923136);       // 32,768 B
    u16*   Wt_b   = (u16*)(wsb + 104955904);       // 163,840 B

    k0_init<<<dim3(448), dim3(256), 0, stream>>>(Wd, Wt, statsY, statsZ, WdB, Wt_b);
    k1a_gcn<<<dim3(16, 128), dim3(256), 0, stream>>>(x, PA, gT);
    k1b_mfma<<<dim3(50, 32), dim3(256), 0, stream>>>(gT, WdB, bd, y0b, statsY);
    k2_yhat<<<dim3(25, 128), dim3(256), 0, stream>>>(y0b, x, statsY, yhatT);
    k3_mfma<<<dim3(1600), dim3(256), 0, stream>>>(yhatT, Wt_b, bt, zb, statsZ);
    k4_final<<<dim3(12800), dim3(256), 0, stream>>>(zb, x, statsZ, out);
}

// Round 12
// 355.841 us; speedup vs baseline: 1.0216x; 1.0216x over previous
//
#include <hip/hip_runtime.h>

// GCN-TCN unit. All GEMM-shaped work on bf16 MFMA; swizzled global layouts
// (chunk q of each 64B row stored at position q ^ key(row), key(r) = (r^(r>>2))&3)
// kill LDS bank conflicts while keeping global_load_lds staging purely linear.
// Shapes: N=32, C=128, T=256, V=25, K=5.
//
//   k0 : init stats, Wd -> WdB bf16 linear, Wt -> Wt_b bf16 swz(o)
//   k1a: g = x@PA -> gT bf16 [n][cc][col][c32]~swz(col)  (PA transposed in LDS;
//        vectorized output: ds_read_b128 + dwordx4, rows padded to 20 dw)
//   k1b: y0 = Wd@g + bd -> y0b bf16 + statsY   (MFMA K=128, B dbuf, A from global/L2)
//   k2 : yhat = relu(inorm(y0)+x) -> yhatT ~swz(col)  (aliases gT)
//   k3 : z = conv(yhat) + bt -> zb bf16 (aliases y0b) + statsZ
//        (r5-converged: 64o x 256c, grid 1600, 3 blocks/CU, A LDS-staged,
//         B reg-prefetch w/ counted vmcnt, XCD swizzle, setprio)
//   k4 : out = relu(inorm(z)+x) -> d_out fp32
//
// Ledger: r6 xb refuted (x L3-resident); r7 A-direct+1-barrier spilled; r8 128c
// tile refuted (per-phase-overhead bound); r11 nontemporal-k4 + gather-k2 refuted
// (both at BW/issue floor). k3 converged at r5 config; this file = r9 best state.

typedef unsigned short u16;
typedef unsigned int   u32;

using short8  = __attribute__((ext_vector_type(8))) short;
using floatx4 = __attribute__((ext_vector_type(4))) float;
using u32x4   = __attribute__((ext_vector_type(4))) unsigned int;

#define NBATCH 32
#define CH     128
#define TDIM   256
#define VDIM   25
#define KT     5
#define PLANE  6400
#define EPSF   1e-5f
#define INV_PLANE (1.0f/6400.0f)

__device__ __forceinline__ u16 f2bf(float f) {          // RNE fp32 -> bf16
    u32 u = __float_as_uint(f);
    return (u16)((u + 0x7fffu + ((u >> 16) & 1u)) >> 16);
}
__device__ __forceinline__ float bf2f(u16 h) {
    return __uint_as_float(((u32)h) << 16);
}
__device__ __forceinline__ void gload_lds16(const void* g, void* l) {
    __builtin_amdgcn_global_load_lds(
        (const __attribute__((address_space(1))) u32*)g,
        (__attribute__((address_space(3))) u32*)l, 16, 0, 0);
}

// ---------------- K0: init stats + weight repack ----------------
// WdB linear (k1b reads fragments straight from global/L2).
// Wt_b swizzled with key(o) = (o^(o>>2))&3 (k3 stages linearly; reads use key).
__global__ __launch_bounds__(256) void k0_init(
    const float* __restrict__ Wd, const float* __restrict__ Wt,
    float* __restrict__ statsY, float* __restrict__ statsZ,
    u16* __restrict__ WdB, u16* __restrict__ Wt_b)
{
    int i = blockIdx.x * 256 + threadIdx.x;       // grid covers exactly 114688
    if (i < 8192) {
        statsY[i] = 0.f;
    } else if (i < 16384) {
        statsZ[i - 8192] = 0.f;
    } else if (i < 32768) {
        int j  = i - 16384;                       // WdB[cc][o][c32] linear
        int sl = j & 31;
        int o  = (j >> 5) & 127;
        int cc = j >> 12;
        WdB[j] = f2bf(Wd[o * CH + cc * 32 + sl]);
    } else {
        int j  = i - 32768;                       // Wt_b[ic][tap][o][stored i-slot]~swz(o)
        int sl = j & 31;
        int o  = (j >> 5) & 127;
        int r2 = j >> 12;
        int tap = r2 % KT;
        int ic  = r2 / KT;
        int ko = ((o ^ (o >> 2)) & 3);
        int il = (((sl >> 3) ^ ko) << 3) | (sl & 7);
        Wt_b[j] = f2bf(Wt[(o * CH + ic * 32 + il) * KT + tap]);
    }
}

// ---------------- K1a: g = x@PA -> gT bf16 [n][cc][col][c32]~swz ----------------
// grid (16, 128): blockIdx.x = 400-col chunk (16 t-rows), blockIdx.y = n*4+cc.
// PA stored transposed+padded (sPA[v*28+w]) so the inner loop reads stride-1.
// sG rows padded to 20 dwords; output stage moves whole 16B q-chunks.
__global__ __launch_bounds__(256) void k1a_gcn(
    const float* __restrict__ x, const float* __restrict__ PA,
    u16* __restrict__ gT)
{
    __shared__ __attribute__((aligned(16))) u32 sG[400 * 20];  // 400 rows x 20 dw (pad)
    __shared__ __attribute__((aligned(16))) float sPA[700];    // [v][28] transposed

    const int tid   = threadIdx.x;
    const int nic   = blockIdx.y;
    const int chunk = blockIdx.x;
    const int c0    = chunk * 400;                // 400 = 0 mod 16 -> local key form OK
    const int cl    = tid >> 3;
    const int tl    = tid & 7;

    for (int i = tid; i < 700; i += 256) {
        int v = i / 28, w = i % 28;
        sPA[i] = (w < VDIM) ? PA[w * VDIM + v] : 0.f;
    }

    const float* xrow = x + (size_t)(nic * 32 + cl) * PLANE + c0 + tl * 50;
    float xr[50];
#pragma unroll
    for (int w = 0; w < 25; ++w) {
        float2 t2 = *(const float2*)(xrow + 2 * w);
        xr[2 * w]     = t2.x;
        xr[2 * w + 1] = t2.y;
    }
    __syncthreads();

    u16* sG16 = (u16*)sG;
#pragma unroll
    for (int v = 0; v < VDIM; ++v) {
        float g0 = 0.f, g1 = 0.f;
        const float* pav = &sPA[v * 28];
#pragma unroll
        for (int w = 0; w < VDIM; ++w) {
            float p = pav[w];                     // stride-1, wave-uniform broadcast
            g0 += xr[w] * p;
            g1 += xr[25 + w] * p;
        }
        int r0 = tl * 50 + v;
        sG16[r0 * 40 + cl]        = f2bf(g0);
        sG16[(r0 + 25) * 40 + cl] = f2bf(g1);
    }
    __syncthreads();

    u32* outd = (u32*)gT;
    const size_t ob = ((size_t)nic * PLANE + c0) * 16;
    for (int g4 = tid; g4 < 1600; g4 += 256) {    // 1600 16B q-chunks
        int r = g4 >> 2, q = g4 & 3;
        int kr = ((r ^ (r >> 2)) & 3);
        u32x4 v = *(const u32x4*)(sG + r * 20 + q * 4);
        *(u32x4*)(outd + ob + r * 16 + ((q ^ kr) << 2)) = v;
    }
}

// ---------------- K1b: y0 = Wd@g + bd via bf16 MFMA, K=128 ----------------
__global__ __launch_bounds__(256) void k1b_mfma(
    const u16* __restrict__ gT, const u16* __restrict__ WdB,
    const float* __restrict__ bd,
    u16* __restrict__ y0b, float* __restrict__ statsY)
{
    __shared__ __attribute__((aligned(16))) char lds[16384];   // 2 x 8KB B buffers

    const int tid  = threadIdx.x;
    const int wave = tid >> 6;
    const int lane = tid & 63;
    const int l    = lane & 15;
    const int quad = lane >> 4;
    const int n    = blockIdx.y;
    const int c0   = blockIdx.x * 128;            // mult of 16 -> local key form OK
    const int wub  = tid & ~63;

    auto stageB = [&](int cc, char* dst) {
        const char* bsrc = (const char*)gT + ((size_t)(n * 4 + cc) * PLANE + c0) * 64;
#pragma unroll
        for (int it = 0; it < 2; ++it)
            gload_lds16(bsrc + (it * 256 + tid) * 16, dst + (it * 256 + wub) * 16);
    };

    stageB(0, lds);
    __syncthreads();

    floatx4 acc[2][8];
#pragma unroll
    for (int a = 0; a < 2; ++a)
#pragma unroll
        for (int b = 0; b < 8; ++b) acc[a][b] = (floatx4){0.f, 0.f, 0.f, 0.f};

    for (int cc = 0; cc < 4; ++cc) {
        char* const sBc = lds + (cc & 1) * 8192;
        char* const sBn = lds + ((cc + 1) & 1) * 8192;

        // A fragments from global: lanes cover 16 consecutive 64B rows (coalesced)
        const char* abase = (const char*)WdB + cc * 8192 + (wave * 32 + l) * 64 + (quad << 4);
        const short8 a0 = *(const short8*)(abase);
        const short8 a1 = *(const short8*)(abase + 16 * 64);
        __builtin_amdgcn_sched_barrier(0);        // af loads issue before staging

        if (cc < 3) stageB(cc + 1, sBn);

#pragma unroll
        for (int ct = 0; ct < 8; ++ct) {
            const int r = ct * 16 + l;
            const short8 b = *(const short8*)(sBc + r * 64 + ((quad ^ ((r ^ (r >> 2)) & 3)) << 4));
            acc[0][ct] = __builtin_amdgcn_mfma_f32_16x16x32_bf16(a0, b, acc[0][ct], 0, 0, 0);
            acc[1][ct] = __builtin_amdgcn_mfma_f32_16x16x32_bf16(a1, b, acc[1][ct], 0, 0, 0);
        }
        __syncthreads();
    }

#pragma unroll
    for (int ot = 0; ot < 2; ++ot) {
#pragma unroll
        for (int reg = 0; reg < 4; ++reg) {
            const int o = wave * 32 + ot * 16 + quad * 4 + reg;
            const float bias = bd[o];
            float s1 = 0.f, s2 = 0.f;
            u16* yp = y0b + (size_t)(n * CH + o) * PLANE + c0 + l;
#pragma unroll
            for (int ct = 0; ct < 8; ++ct) {
                float val = acc[ot][ct][reg] + bias;
                yp[ct * 16] = f2bf(val);
                s1 += val; s2 += val * val;
            }
#pragma unroll
            for (int m = 1; m <= 8; m <<= 1) {
                s1 += __shfl_xor(s1, m, 64);
                s2 += __shfl_xor(s2, m, 64);
            }
            if (l == 0) {
                atomicAdd(&statsY[(n * CH + o) * 2 + 0], s1);
                atomicAdd(&statsY[(n * CH + o) * 2 + 1], s2);
            }
        }
    }
}

// ---------------- K2: yhat = relu(inorm(y0)+x) -> yhatT bf16 ~swz ----------------
__global__ __launch_bounds__(256) void k2_yhat(
    const u16* __restrict__ y0b, const float* __restrict__ x,
    const float* __restrict__ statsY, u16* __restrict__ yhatT)
{
    __shared__ u32 sT[256 * 17];
    __shared__ float sM[32], sR[32];

    const int tid = threadIdx.x;
    const int nic = blockIdx.y;
    const int n   = nic >> 2, ic = nic & 3;
    const int c0  = blockIdx.x * 256;             // mult of 16 -> local key form OK

    if (tid < 32) {
        float a = statsY[(n * CH + ic * 32 + tid) * 2 + 0];
        float b = statsY[(n * CH + ic * 32 + tid) * 2 + 1];
        float m = a * INV_PLANE;
        sM[tid] = m;
        sR[tid] = rsqrtf(b * INV_PLANE - m * m + EPSF);
    }
    __syncthreads();

    u16* sT16 = (u16*)sT;
#pragma unroll
    for (int k = 0; k < 4; ++k) {
        int j  = k * 256 + tid;                   // 0..1023
        int ch = j >> 5;                          // 0..31
        int cb = (j & 31) << 3;                   // col base, 8-aligned
        int g  = (n * CH + ic * 32 + ch) * PLANE + c0 + cb;
        short8 yv = *(const short8*)(y0b + g);
        const float4* xp = (const float4*)(x + g);
        float4 x0 = xp[0], x1 = xp[1];
        float xf[8];
        xf[0] = x0.x; xf[1] = x0.y; xf[2] = x0.z; xf[3] = x0.w;
        xf[4] = x1.x; xf[5] = x1.y; xf[6] = x1.z; xf[7] = x1.w;
        float m = sM[ch], r = sR[ch];
        int wp = ((ch >> 1) ^ ((cb >> 3) & 15));  // swizzled pair index
        u16* dst = sT16 + cb * 34 + wp * 2 + (ch & 1);
#pragma unroll
        for (int e = 0; e < 8; ++e)
            dst[e * 34] = f2bf(fmaxf((bf2f((u16)yv[e]) - m) * r + xf[e], 0.f));
    }
    __syncthreads();

    u32* outd = (u32*)yhatT;
    int obase = (nic * PLANE + c0) * 16;
    for (int idx = tid; idx < 4096; idx += 256) {
        int r = idx >> 4, dw = idx & 15;
        int q = dw >> 2, b = dw & 3;
        u32 val = sT[r * 17 + ((dw ^ (r >> 3)) & 15)];      // un-swizzle pair index
        int kr = ((r ^ (r >> 2)) & 3);
        outd[obase + r * 16 + (((q ^ kr) << 2) | b)] = val;
    }
}

// ---------------- K3: TCN conv via bf16 MFMA, 64o x 256c blocks (r5) ----------------
// grid 1600 (1D, XCD-swizzled): id&7 = XCD, each XCD owns n in [4*xcd, 4*xcd+4).
// 4 waves, each 32o x 128c -> acc[2][8] = 64 AGPRs; LDS 45KB -> 3 blocks/CU.
// B register-prefetch pipeline w/ counted vmcnt (5 A-DMAs + 6 B-loads in flight
// -> vmcnt(6) drains exactly A, keeps B in flight). LDS reads use (r>>2)-folded
// key; local B rows at global offset c0-100 -> local key (r&3)^(((r>>2)+3)&3).
__global__ __launch_bounds__(256, 3) void k3_mfma(
    const u16* __restrict__ yhatT, const u16* __restrict__ Wt_b,
    const float* __restrict__ bt,
    u16* __restrict__ zb, float* __restrict__ statsZ)
{
    __shared__ __attribute__((aligned(16))) char lds[45056];
    char* const sA = lds;            // [tap][64 o][32 i] bf16 = 20480 B
    char* const sB = lds + 20480;    // [row 0..384)[32 i] bf16 = 24576 B

    const int tid  = threadIdx.x;
    const int wave = tid >> 6;
    const int wr2  = wave >> 1;      // 32-o half within the block's 64 o
    const int wc   = wave & 1;       // col 128-half
    const int lane = tid & 63;
    const int l    = lane & 15;
    const int quad = lane >> 4;
    const int id   = blockIdx.x;     // XCD-aware decomposition (1600 blocks)
    const int xcd  = id & 7;
    const int jj   = id >> 3;        // 0..199
    const int n    = xcd * 4 + jj / 50;
    const int rem  = jj % 50;
    const int oh   = rem / 25;       // which 64-o half
    const int blk  = rem % 25;
    const int c0   = blk * 256;
    const int wub  = tid & ~63;
    const bool mainp = (blk != 0);

    floatx4 acc[2][8];
#pragma unroll
    for (int a = 0; a < 2; ++a)
#pragma unroll
        for (int b = 0; b < 8; ++b) acc[a][b] = (floatx4){0.f, 0.f, 0.f, 0.f};

    auto bsrcIC = [&](int ic) -> const char* {
        return (const char*)yhatT + ((size_t)(n * 4 + ic) * PLANE) * 64
             + (size_t)(c0 - 100) * 64;
    };

    short8 breg[6];
    if (mainp) {
#pragma unroll
        for (int it = 0; it < 6; ++it)
            breg[it] = *(const short8*)(bsrcIC(0) + (it * 256 + tid) * 16);
    }

    for (int ic = 0; ic < 4; ++ic) {
        __syncthreads();             // prev MFMA consumed LDS; drains all counters

        // stage A: 5 taps x 4096 B async DMA (L2-resident weights, this o-half)
#pragma unroll
        for (int tap = 0; tap < KT; ++tap)
            gload_lds16((const char*)Wt_b + ic * 40960 + (tap * 128 + oh * 64) * 64 + tid * 16,
                        sA + tap * 4096 + wub * 16);
        __builtin_amdgcn_sched_barrier(0);        // A issues first (oldest in queue)

        if (mainp) {
            // write current B tile from regs (compiler waits breg deps)
#pragma unroll
            for (int it = 0; it < 6; ++it)
                *((short8*)(sB + (it * 256 + tid) * 16)) = breg[it];
            if (ic < 3) {
                const char* nb = bsrcIC(ic + 1);
                __builtin_amdgcn_sched_barrier(0);
#pragma unroll
                for (int it = 0; it < 6; ++it)    // exactly 6 vm ops, newest
                    breg[it] = *(const short8*)(nb + (it * 256 + tid) * 16);
                __builtin_amdgcn_sched_barrier(0);
                asm volatile("s_waitcnt vmcnt(6) lgkmcnt(0)" ::: "memory");
            } else {
                asm volatile("s_waitcnt vmcnt(0) lgkmcnt(0)" ::: "memory");
            }
        } else {
            // blk==0: rows 100..356 <- cols 0..256 via DMA; rows 0..100 reflected
            const char* bsrc = (const char*)yhatT + ((size_t)(n * 4 + ic) * PLANE) * 64;
#pragma unroll
            for (int it = 0; it < 4; ++it)
                gload_lds16(bsrc + (it * 256 + tid) * 16, sB + 6400 + (it * 256 + wub) * 16);
            const u32* bsrcd = (const u32*)bsrc;
            u32* sBd = (u32*)sB;
            for (int idx = tid; idx < 1600; idx += 256) {
                int r = idx >> 4, dw = idx & 15;
                int q = dw >> 2, b = dw & 3;
                int d = 100 - r;
                int tref = (d + 24) / 25;
                int v = r % 25;
                int sc = tref * 25 + v;
                int kd = ((r ^ ((r >> 2) + 3)) & 3);        // local-key for dst row
                int ks = ((sc ^ (sc >> 2)) & 3);            // global-key for src row
                sBd[r * 16 + (((q ^ kd) << 2) | b)] =
                    bsrcd[sc * 16 + (((q ^ ks) << 2) | b)];
            }
            asm volatile("s_waitcnt vmcnt(0) lgkmcnt(0)" ::: "memory");
        }
        __builtin_amdgcn_s_barrier();
        __builtin_amdgcn_sched_barrier(0);        // pin ds_reads below the barrier

        __builtin_amdgcn_s_setprio(1);
#pragma unroll
        for (int tap = 0; tap < KT; ++tap) {
            short8 af[2];
#pragma unroll
            for (int ot = 0; ot < 2; ++ot) {
                int ro = wr2 * 32 + ot * 16 + l;
                af[ot] = *(const short8*)(sA + tap * 4096 + ro * 64
                                          + ((quad ^ ((ro ^ (ro >> 2)) & 3)) << 4));
            }
#pragma unroll
            for (int ct = 0; ct < 8; ++ct) {
                int r = wc * 128 + ct * 16 + l + tap * 25;
                const short8 b = *(const short8*)(sB + r * 64
                                          + ((quad ^ ((r ^ ((r >> 2) + 3)) & 3)) << 4));
#pragma unroll
                for (int ot = 0; ot < 2; ++ot)
                    acc[ot][ct] = __builtin_amdgcn_mfma_f32_16x16x32_bf16(af[ot], b, acc[ot][ct], 0, 0, 0);
            }
        }
        __builtin_amdgcn_s_setprio(0);
    }

    // epilogue: bias + bf16 store + stats (C/D: col=lane&15, row=quad*4+reg)
#pragma unroll
    for (int ot = 0; ot < 2; ++ot) {
#pragma unroll
        for (int reg = 0; reg < 4; ++reg) {
            const int o = oh * 64 + wr2 * 32 + ot * 16 + quad * 4 + reg;
            const float bias = bt[o];
            float s1 = 0.f, s2 = 0.f;
            u16* zp = zb + (size_t)(n * CH + o) * PLANE + c0 + wc * 128 + l;
#pragma unroll
            for (int ct = 0; ct < 8; ++ct) {
                float val = acc[ot][ct][reg] + bias;
                zp[ct * 16] = f2bf(val);
                s1 += val; s2 += val * val;
            }
#pragma unroll
            for (int m = 1; m <= 8; m <<= 1) {
                s1 += __shfl_xor(s1, m, 64);
                s2 += __shfl_xor(s2, m, 64);
            }
            if (l == 0) {
                atomicAdd(&statsZ[(n * CH + o) * 2 + 0], s1);
                atomicAdd(&statsZ[(n * CH + o) * 2 + 1], s2);
            }
        }
    }
}

// ---------------- K4: out = relu(inorm(zb) + x) -> d_out ----------------
__global__ __launch_bounds__(256) void k4_final(
    const u16* __restrict__ zb, const float* __restrict__ x,
    const float* __restrict__ statsZ, float* __restrict__ out)
{
    int g = blockIdx.x * 256 + threadIdx.x;       // 3,276,800 threads x 8 elems
    int p = g / 800;
    float a = statsZ[p * 2 + 0], b = statsZ[p * 2 + 1];
    float m = a * INV_PLANE;
    float r = rsqrtf(b * INV_PLANE - m * m + EPSF);
    short8 zv = *(const short8*)(zb + (size_t)g * 8);
    const float4* xp = (const float4*)x + (size_t)g * 2;
    float4 x0 = xp[0], x1 = xp[1];
    float4 o0, o1;
    o0.x = fmaxf((bf2f((u16)zv[0]) - m) * r + x0.x, 0.f);
    o0.y = fmaxf((bf2f((u16)zv[1]) - m) * r + x0.y, 0.f);
    o0.z = fmaxf((bf2f((u16)zv[2]) - m) * r + x0.z, 0.f);
    o0.w = fmaxf((bf2f((u16)zv[3]) - m) * r + x0.w, 0.f);
    o1.x = fmaxf((bf2f((u16)zv[4]) - m) * r + x1.x, 0.f);
    o1.y = fmaxf((bf2f((u16)zv[5]) - m) * r + x1.y, 0.f);
    o1.z = fmaxf((bf2f((u16)zv[6]) - m) * r + x1.z, 0.f);
    o1.w = fmaxf((bf2f((u16)zv[7]) - m) * r + x1.w, 0.f);
    float4* op = (float4*)out + (size_t)g * 2;
    op[0] = o0;
    op[1] = o1;
}

extern "C" void kernel_launch(void* const* d_in, const int* in_sizes, int n_in,
                              void* d_out, int out_size, void* d_ws, size_t ws_size,
                              hipStream_t stream) {
    const float* x  = (const float*)d_in[0];
    const float* PA = (const float*)d_in[1];
    const float* Wd = (const float*)d_in[2];
    const float* bd = (const float*)d_in[3];
    const float* Wt = (const float*)d_in[4];
    const float* bt = (const float*)d_in[5];
    float* out = (float*)d_out;

    char* wsb = (char*)d_ws;
    u16*   y0b    = (u16*)(wsb);                   // 52,428,800 B (aliased by zb)
    u16*   zb     = y0b;                           //   y0b consumed by k2 before k3 writes
    u16*   gT     = (u16*)(wsb + 52428800);        // 52,428,800 B (aliased by yhatT)
    u16*   yhatT  = gT;                            //   gT consumed by k1b before k2 writes
    float* statsY = (float*)(wsb + 104857600);     // 32,768 B
    float* statsZ = (float*)(wsb + 104890368);     // 32,768 B
    u16*   WdB    = (u16*)(wsb + 104923136);       // 32,768 B
    u16*   Wt_b   = (u16*)(wsb + 104955904);       // 163,840 B

    k0_init<<<dim3(448), dim3(256), 0, stream>>>(Wd, Wt, statsY, statsZ, WdB, Wt_b);
    k1a_gcn<<<dim3(16, 128), dim3(256), 0, stream>>>(x, PA, gT);
    k1b_mfma<<<dim3(50, 32), dim3(256), 0, stream>>>(gT, WdB, bd, y0b, statsY);
    k2_yhat<<<dim3(25, 128), dim3(256), 0, stream>>>(y0b, x, statsY, yhatT);
    k3_mfma<<<dim3(1600), dim3(256), 0, stream>>>(yhatT, Wt_b, bt, zb, statsZ);
    k4_final<<<dim3(12800), dim3(256), 0, stream>>>(zb, x, statsZ, out);
}